// Round 1
// baseline (264.613 us; speedup 1.0000x reference)
//
#include <hip/hip_runtime.h>

// Problem constants (fixed by the reference): x(16,3,512,512) fp32
#define HW_   (512 * 512)   // 262144 = 2^18
#define N_    16
#define C_    3
#define NHW_  (N_ * HW_)    // 4194304 = 2^22
#define BF_THRESH 0.5f

__global__ void wmse_zero_ws(float* ws) {
    if (threadIdx.x < 3) ws[threadIdx.x] = 0.0f;
}

__global__ __launch_bounds__(256) void wmse_reduce(
    const float* __restrict__ x,
    const float* __restrict__ ae,
    const float* __restrict__ seg,
    float* __restrict__ ws)
{
    const int gtid   = blockIdx.x * blockDim.x + threadIdx.x;
    const int stride = gridDim.x * blockDim.x;
    const int num_vec = NHW_ / 4;  // float4 groups over (n,hw)

    float pos_sum = 0.0f, neg_sum = 0.0f, pos_cnt = 0.0f;

    for (int v = gtid; v < num_vec; v += stride) {
        const int pos = v << 2;             // flat (n*HW + hw)
        const int n   = pos >> 18;          // / HW_
        const int hw  = pos & (HW_ - 1);    // % HW_

        const float4 s = *reinterpret_cast<const float4*>(seg + pos);
        const float p0 = s.x > BF_THRESH ? 1.0f : 0.0f;
        const float p1 = s.y > BF_THRESH ? 1.0f : 0.0f;
        const float p2 = s.z > BF_THRESH ? 1.0f : 0.0f;
        const float p3 = s.w > BF_THRESH ? 1.0f : 0.0f;
        pos_cnt += p0 + p1 + p2 + p3;

        const int base = n * (C_ * HW_) + hw;   // max ~12.6M, fits int32
#pragma unroll
        for (int c = 0; c < C_; ++c) {
            const int off = base + c * HW_;
            const float4 xv = *reinterpret_cast<const float4*>(x  + off);
            const float4 av = *reinterpret_cast<const float4*>(ae + off);
            const float d0 = av.x - xv.x, d1 = av.y - xv.y;
            const float d2 = av.z - xv.z, d3 = av.w - xv.w;
            const float q0 = d0 * d0, q1 = d1 * d1, q2 = d2 * d2, q3 = d3 * d3;
            const float qsum = q0 + q1 + q2 + q3;
            const float psum = q0 * p0 + q1 * p1 + q2 * p2 + q3 * p3;
            pos_sum += psum;
            neg_sum += qsum - psum;
        }
    }

    // wave-64 shuffle tree
#pragma unroll
    for (int off = 32; off >= 1; off >>= 1) {
        pos_sum += __shfl_down(pos_sum, off, 64);
        neg_sum += __shfl_down(neg_sum, off, 64);
        pos_cnt += __shfl_down(pos_cnt, off, 64);
    }

    __shared__ float sp[4], sn[4], sc[4];
    const int wave = threadIdx.x >> 6;
    const int lane = threadIdx.x & 63;
    if (lane == 0) { sp[wave] = pos_sum; sn[wave] = neg_sum; sc[wave] = pos_cnt; }
    __syncthreads();
    if (threadIdx.x == 0) {
        const float tp = sp[0] + sp[1] + sp[2] + sp[3];
        const float tn = sn[0] + sn[1] + sn[2] + sn[3];
        const float tc = sc[0] + sc[1] + sc[2] + sc[3];
        atomicAdd(&ws[0], tp);
        atomicAdd(&ws[1], tn);
        atomicAdd(&ws[2], tc);
    }
}

__global__ void wmse_finalize(const float* __restrict__ ws, float* __restrict__ out) {
    if (threadIdx.x == 0) {
        const float pos_sum = ws[0];
        const float neg_sum = ws[1];
        const float pos_num = ws[2];
        const float total   = (float)NHW_;
        const float neg_num = total - pos_num;
        const float pos_ratio = pos_num / total;
        const float neg_ratio = 1.0f - pos_ratio;
        const float mse_pos = pos_sum / (pos_num * (float)C_);
        const float mse_neg = neg_sum / (neg_num * (float)C_);
        out[0] = pos_ratio * mse_neg + neg_ratio * mse_pos;
    }
}

extern "C" void kernel_launch(void* const* d_in, const int* in_sizes, int n_in,
                              void* d_out, int out_size, void* d_ws, size_t ws_size,
                              hipStream_t stream) {
    const float* x   = (const float*)d_in[0];
    const float* ae  = (const float*)d_in[1];
    const float* seg = (const float*)d_in[2];
    float* ws  = (float*)d_ws;
    float* out = (float*)d_out;

    wmse_zero_ws<<<1, 64, 0, stream>>>(ws);

    // 4096 blocks x 256 threads = 1,048,576 threads = num_vec (1 iter/thread)
    const int block = 256;
    const int grid  = 4096;
    wmse_reduce<<<grid, block, 0, stream>>>(x, ae, seg, ws);

    wmse_finalize<<<1, 64, 0, stream>>>(ws, out);
}

// Round 2
// 137.158 us; speedup vs baseline: 1.9293x; 1.9293x over previous
//
#include <hip/hip_runtime.h>

// Problem constants (fixed by the reference): x(16,3,512,512) fp32
#define HW_   (512 * 512)   // 262144 = 2^18
#define N_    16
#define C_    3
#define NHW_  (N_ * HW_)    // 4194304 = 2^22
#define BF_THRESH 0.5f

#define GRID1 2048          // stage-1 blocks: 2048 x 4 waves = 8192 = full residency

__global__ __launch_bounds__(256) void wmse_reduce(
    const float* __restrict__ x,
    const float* __restrict__ ae,
    const float* __restrict__ seg,
    float* __restrict__ ws)   // ws[0..GRID1): pos_sum, [GRID1..2*GRID1): neg_sum, [2*GRID1..3*GRID1): cnt
{
    const int gtid   = blockIdx.x * blockDim.x + threadIdx.x;
    const int stride = GRID1 * 256;
    const int num_vec = NHW_ / 4;  // float4 groups over (n,hw)

    float pos_sum = 0.0f, neg_sum = 0.0f, pos_cnt = 0.0f;

    for (int v = gtid; v < num_vec; v += stride) {
        const int pos = v << 2;             // flat (n*HW + hw)
        const int n   = pos >> 18;          // / HW_
        const int hw  = pos & (HW_ - 1);    // % HW_

        const float4 s = *reinterpret_cast<const float4*>(seg + pos);
        const float p0 = s.x > BF_THRESH ? 1.0f : 0.0f;
        const float p1 = s.y > BF_THRESH ? 1.0f : 0.0f;
        const float p2 = s.z > BF_THRESH ? 1.0f : 0.0f;
        const float p3 = s.w > BF_THRESH ? 1.0f : 0.0f;
        pos_cnt += p0 + p1 + p2 + p3;

        const int base = n * (C_ * HW_) + hw;   // max ~12.6M, fits int32
#pragma unroll
        for (int c = 0; c < C_; ++c) {
            const int off = base + c * HW_;
            const float4 xv = *reinterpret_cast<const float4*>(x  + off);
            const float4 av = *reinterpret_cast<const float4*>(ae + off);
            const float d0 = av.x - xv.x, d1 = av.y - xv.y;
            const float d2 = av.z - xv.z, d3 = av.w - xv.w;
            const float q0 = d0 * d0, q1 = d1 * d1, q2 = d2 * d2, q3 = d3 * d3;
            const float qsum = q0 + q1 + q2 + q3;
            const float psum = q0 * p0 + q1 * p1 + q2 * p2 + q3 * p3;
            pos_sum += psum;
            neg_sum += qsum - psum;
        }
    }

    // wave-64 shuffle tree
#pragma unroll
    for (int off = 32; off >= 1; off >>= 1) {
        pos_sum += __shfl_down(pos_sum, off, 64);
        neg_sum += __shfl_down(neg_sum, off, 64);
        pos_cnt += __shfl_down(pos_cnt, off, 64);
    }

    __shared__ float sp[4], sn[4], sc[4];
    const int wave = threadIdx.x >> 6;
    const int lane = threadIdx.x & 63;
    if (lane == 0) { sp[wave] = pos_sum; sn[wave] = neg_sum; sc[wave] = pos_cnt; }
    __syncthreads();
    if (threadIdx.x == 0) {
        ws[blockIdx.x]             = sp[0] + sp[1] + sp[2] + sp[3];
        ws[GRID1 + blockIdx.x]     = sn[0] + sn[1] + sn[2] + sn[3];
        ws[2 * GRID1 + blockIdx.x] = sc[0] + sc[1] + sc[2] + sc[3];
    }
}

__global__ __launch_bounds__(256) void wmse_stage2(
    const float* __restrict__ ws, float* __restrict__ out)
{
    float pos_sum = 0.0f, neg_sum = 0.0f, pos_cnt = 0.0f;
    // 2048 partials per array, 256 threads -> 8 each
    for (int i = threadIdx.x; i < GRID1; i += 256) {
        pos_sum += ws[i];
        neg_sum += ws[GRID1 + i];
        pos_cnt += ws[2 * GRID1 + i];
    }

#pragma unroll
    for (int off = 32; off >= 1; off >>= 1) {
        pos_sum += __shfl_down(pos_sum, off, 64);
        neg_sum += __shfl_down(neg_sum, off, 64);
        pos_cnt += __shfl_down(pos_cnt, off, 64);
    }

    __shared__ float sp[4], sn[4], sc[4];
    const int wave = threadIdx.x >> 6;
    const int lane = threadIdx.x & 63;
    if (lane == 0) { sp[wave] = pos_sum; sn[wave] = neg_sum; sc[wave] = pos_cnt; }
    __syncthreads();
    if (threadIdx.x == 0) {
        const float tp = sp[0] + sp[1] + sp[2] + sp[3];
        const float tn = sn[0] + sn[1] + sn[2] + sn[3];
        const float tc = sc[0] + sc[1] + sc[2] + sc[3];

        const float total   = (float)NHW_;
        const float neg_num = total - tc;
        const float pos_ratio = tc / total;
        const float neg_ratio = 1.0f - pos_ratio;
        const float mse_pos = tp / (tc * (float)C_);
        const float mse_neg = tn / (neg_num * (float)C_);
        out[0] = pos_ratio * mse_neg + neg_ratio * mse_pos;
    }
}

extern "C" void kernel_launch(void* const* d_in, const int* in_sizes, int n_in,
                              void* d_out, int out_size, void* d_ws, size_t ws_size,
                              hipStream_t stream) {
    const float* x   = (const float*)d_in[0];
    const float* ae  = (const float*)d_in[1];
    const float* seg = (const float*)d_in[2];
    float* ws  = (float*)d_ws;
    float* out = (float*)d_out;

    wmse_reduce<<<GRID1, 256, 0, stream>>>(x, ae, seg, ws);
    wmse_stage2<<<1, 256, 0, stream>>>(ws, out);
}

// Round 3
// 136.091 us; speedup vs baseline: 1.9444x; 1.0078x over previous
//
#include <hip/hip_runtime.h>

// Problem constants (fixed by the reference): x(16,3,512,512) fp32
#define HW_   (512 * 512)   // 262144 = 2^18
#define N_    16
#define C_    3
#define NHW_  (N_ * HW_)    // 4194304 = 2^22
#define BF_THRESH 0.5f

#define GRID1   2048        // 2048 blocks x 4 waves = 8192 waves = full residency
#define THREADS 256
#define NVEC    (NHW_ / 4)              // 1048576 float4 groups
#define STRIDE  (GRID1 * THREADS)       // 524288 threads -> exactly 2 groups/thread

__device__ __forceinline__ void wmse_accum(const float4& s,
                                           const float4& x0, const float4& a0,
                                           const float4& x1, const float4& a1,
                                           const float4& x2, const float4& a2,
                                           float& pos_sum, float& neg_sum, float& pos_cnt)
{
    const float p0 = s.x > BF_THRESH ? 1.0f : 0.0f;
    const float p1 = s.y > BF_THRESH ? 1.0f : 0.0f;
    const float p2 = s.z > BF_THRESH ? 1.0f : 0.0f;
    const float p3 = s.w > BF_THRESH ? 1.0f : 0.0f;
    pos_cnt += p0 + p1 + p2 + p3;

    float q0, q1, q2, q3, d0, d1, d2, d3, qsum, psum;

    d0 = a0.x - x0.x; d1 = a0.y - x0.y; d2 = a0.z - x0.z; d3 = a0.w - x0.w;
    q0 = d0 * d0; q1 = d1 * d1; q2 = d2 * d2; q3 = d3 * d3;
    qsum = q0 + q1 + q2 + q3;
    psum = q0 * p0 + q1 * p1 + q2 * p2 + q3 * p3;
    pos_sum += psum; neg_sum += qsum - psum;

    d0 = a1.x - x1.x; d1 = a1.y - x1.y; d2 = a1.z - x1.z; d3 = a1.w - x1.w;
    q0 = d0 * d0; q1 = d1 * d1; q2 = d2 * d2; q3 = d3 * d3;
    qsum = q0 + q1 + q2 + q3;
    psum = q0 * p0 + q1 * p1 + q2 * p2 + q3 * p3;
    pos_sum += psum; neg_sum += qsum - psum;

    d0 = a2.x - x2.x; d1 = a2.y - x2.y; d2 = a2.z - x2.z; d3 = a2.w - x2.w;
    q0 = d0 * d0; q1 = d1 * d1; q2 = d2 * d2; q3 = d3 * d3;
    qsum = q0 + q1 + q2 + q3;
    psum = q0 * p0 + q1 * p1 + q2 * p2 + q3 * p3;
    pos_sum += psum; neg_sum += qsum - psum;
}

__global__ __launch_bounds__(THREADS) void wmse_reduce(
    const float* __restrict__ x,
    const float* __restrict__ ae,
    const float* __restrict__ seg,
    float* __restrict__ ws)   // ws[0..G): pos_sum, [G..2G): neg_sum, [2G..3G): cnt
{
    const int gtid = blockIdx.x * THREADS + threadIdx.x;

    // Two float4 groups per thread, addresses computed up front.
    const int posA = gtid << 2;
    const int posB = (gtid + STRIDE) << 2;

    const int nA = posA >> 18, hwA = posA & (HW_ - 1);
    const int nB = posB >> 18, hwB = posB & (HW_ - 1);
    const int baseA = nA * (C_ * HW_) + hwA;
    const int baseB = nB * (C_ * HW_) + hwB;

    // Issue all 14 loads before any compute (ILP: 14 outstanding vmem ops).
    const float4 sA  = *reinterpret_cast<const float4*>(seg + posA);
    const float4 sB  = *reinterpret_cast<const float4*>(seg + posB);
    const float4 xA0 = *reinterpret_cast<const float4*>(x  + baseA);
    const float4 aA0 = *reinterpret_cast<const float4*>(ae + baseA);
    const float4 xA1 = *reinterpret_cast<const float4*>(x  + baseA + HW_);
    const float4 aA1 = *reinterpret_cast<const float4*>(ae + baseA + HW_);
    const float4 xA2 = *reinterpret_cast<const float4*>(x  + baseA + 2 * HW_);
    const float4 aA2 = *reinterpret_cast<const float4*>(ae + baseA + 2 * HW_);
    const float4 xB0 = *reinterpret_cast<const float4*>(x  + baseB);
    const float4 aB0 = *reinterpret_cast<const float4*>(ae + baseB);
    const float4 xB1 = *reinterpret_cast<const float4*>(x  + baseB + HW_);
    const float4 aB1 = *reinterpret_cast<const float4*>(ae + baseB + HW_);
    const float4 xB2 = *reinterpret_cast<const float4*>(x  + baseB + 2 * HW_);
    const float4 aB2 = *reinterpret_cast<const float4*>(ae + baseB + 2 * HW_);

    float pos_sum = 0.0f, neg_sum = 0.0f, pos_cnt = 0.0f;
    wmse_accum(sA, xA0, aA0, xA1, aA1, xA2, aA2, pos_sum, neg_sum, pos_cnt);
    wmse_accum(sB, xB0, aB0, xB1, aB1, xB2, aB2, pos_sum, neg_sum, pos_cnt);

    // wave-64 shuffle tree
#pragma unroll
    for (int off = 32; off >= 1; off >>= 1) {
        pos_sum += __shfl_down(pos_sum, off, 64);
        neg_sum += __shfl_down(neg_sum, off, 64);
        pos_cnt += __shfl_down(pos_cnt, off, 64);
    }

    __shared__ float sp[4], sn[4], sc[4];
    const int wave = threadIdx.x >> 6;
    const int lane = threadIdx.x & 63;
    if (lane == 0) { sp[wave] = pos_sum; sn[wave] = neg_sum; sc[wave] = pos_cnt; }
    __syncthreads();
    if (threadIdx.x == 0) {
        ws[blockIdx.x]             = sp[0] + sp[1] + sp[2] + sp[3];
        ws[GRID1 + blockIdx.x]     = sn[0] + sn[1] + sn[2] + sn[3];
        ws[2 * GRID1 + blockIdx.x] = sc[0] + sc[1] + sc[2] + sc[3];
    }
}

__global__ __launch_bounds__(256) void wmse_stage2(
    const float* __restrict__ ws, float* __restrict__ out)
{
    float pos_sum = 0.0f, neg_sum = 0.0f, pos_cnt = 0.0f;
    for (int i = threadIdx.x; i < GRID1; i += 256) {
        pos_sum += ws[i];
        neg_sum += ws[GRID1 + i];
        pos_cnt += ws[2 * GRID1 + i];
    }

#pragma unroll
    for (int off = 32; off >= 1; off >>= 1) {
        pos_sum += __shfl_down(pos_sum, off, 64);
        neg_sum += __shfl_down(neg_sum, off, 64);
        pos_cnt += __shfl_down(pos_cnt, off, 64);
    }

    __shared__ float sp[4], sn[4], sc[4];
    const int wave = threadIdx.x >> 6;
    const int lane = threadIdx.x & 63;
    if (lane == 0) { sp[wave] = pos_sum; sn[wave] = neg_sum; sc[wave] = pos_cnt; }
    __syncthreads();
    if (threadIdx.x == 0) {
        const float tp = sp[0] + sp[1] + sp[2] + sp[3];
        const float tn = sn[0] + sn[1] + sn[2] + sn[3];
        const float tc = sc[0] + sc[1] + sc[2] + sc[3];

        const float total   = (float)NHW_;
        const float neg_num = total - tc;
        const float pos_ratio = tc / total;
        const float neg_ratio = 1.0f - pos_ratio;
        const float mse_pos = tp / (tc * (float)C_);
        const float mse_neg = tn / (neg_num * (float)C_);
        out[0] = pos_ratio * mse_neg + neg_ratio * mse_pos;
    }
}

extern "C" void kernel_launch(void* const* d_in, const int* in_sizes, int n_in,
                              void* d_out, int out_size, void* d_ws, size_t ws_size,
                              hipStream_t stream) {
    const float* x   = (const float*)d_in[0];
    const float* ae  = (const float*)d_in[1];
    const float* seg = (const float*)d_in[2];
    float* ws  = (float*)d_ws;
    float* out = (float*)d_out;

    wmse_reduce<<<GRID1, THREADS, 0, stream>>>(x, ae, seg, ws);
    wmse_stage2<<<1, 256, 0, stream>>>(ws, out);
}

// Round 4
// 134.952 us; speedup vs baseline: 1.9608x; 1.0084x over previous
//
#include <hip/hip_runtime.h>

// Problem constants (fixed by the reference): x(16,3,512,512) fp32
#define HW_   (512 * 512)   // 262144 = 2^18
#define N_    16
#define C_    3
#define NHW_  (N_ * HW_)    // 4194304 = 2^22
#define BF_THRESH 0.5f

#define GRID1   1024        // 1024 blocks x 4 waves = 4096 waves (16/CU)
#define THREADS 256
#define NVEC    (NHW_ / 4)              // 1048576 float4 groups
#define STRIDE  (GRID1 * THREADS)       // 262144 threads -> exactly 4 groups/thread

__device__ __forceinline__ void wmse_accum(const float4& s,
                                           const float4& x0, const float4& a0,
                                           const float4& x1, const float4& a1,
                                           const float4& x2, const float4& a2,
                                           float& pos_sum, float& neg_sum, float& pos_cnt)
{
    const float p0 = s.x > BF_THRESH ? 1.0f : 0.0f;
    const float p1 = s.y > BF_THRESH ? 1.0f : 0.0f;
    const float p2 = s.z > BF_THRESH ? 1.0f : 0.0f;
    const float p3 = s.w > BF_THRESH ? 1.0f : 0.0f;
    pos_cnt += p0 + p1 + p2 + p3;

    float q0, q1, q2, q3, d0, d1, d2, d3, qsum, psum;

    d0 = a0.x - x0.x; d1 = a0.y - x0.y; d2 = a0.z - x0.z; d3 = a0.w - x0.w;
    q0 = d0 * d0; q1 = d1 * d1; q2 = d2 * d2; q3 = d3 * d3;
    qsum = q0 + q1 + q2 + q3;
    psum = q0 * p0 + q1 * p1 + q2 * p2 + q3 * p3;
    pos_sum += psum; neg_sum += qsum - psum;

    d0 = a1.x - x1.x; d1 = a1.y - x1.y; d2 = a1.z - x1.z; d3 = a1.w - x1.w;
    q0 = d0 * d0; q1 = d1 * d1; q2 = d2 * d2; q3 = d3 * d3;
    qsum = q0 + q1 + q2 + q3;
    psum = q0 * p0 + q1 * p1 + q2 * p2 + q3 * p3;
    pos_sum += psum; neg_sum += qsum - psum;

    d0 = a2.x - x2.x; d1 = a2.y - x2.y; d2 = a2.z - x2.z; d3 = a2.w - x2.w;
    q0 = d0 * d0; q1 = d1 * d1; q2 = d2 * d2; q3 = d3 * d3;
    qsum = q0 + q1 + q2 + q3;
    psum = q0 * p0 + q1 * p1 + q2 * p2 + q3 * p3;
    pos_sum += psum; neg_sum += qsum - psum;
}

// Load+accumulate two float4 groups (vA, vB); all 14 loads issued before compute.
__device__ __forceinline__ void wmse_batch2(
    const float* __restrict__ x, const float* __restrict__ ae,
    const float* __restrict__ seg, int vA, int vB,
    float& pos_sum, float& neg_sum, float& pos_cnt)
{
    const int posA = vA << 2;
    const int posB = vB << 2;
    const int nA = posA >> 18, hwA = posA & (HW_ - 1);
    const int nB = posB >> 18, hwB = posB & (HW_ - 1);
    const int baseA = nA * (C_ * HW_) + hwA;
    const int baseB = nB * (C_ * HW_) + hwB;

    const float4 sA  = *reinterpret_cast<const float4*>(seg + posA);
    const float4 sB  = *reinterpret_cast<const float4*>(seg + posB);
    const float4 xA0 = *reinterpret_cast<const float4*>(x  + baseA);
    const float4 aA0 = *reinterpret_cast<const float4*>(ae + baseA);
    const float4 xA1 = *reinterpret_cast<const float4*>(x  + baseA + HW_);
    const float4 aA1 = *reinterpret_cast<const float4*>(ae + baseA + HW_);
    const float4 xA2 = *reinterpret_cast<const float4*>(x  + baseA + 2 * HW_);
    const float4 aA2 = *reinterpret_cast<const float4*>(ae + baseA + 2 * HW_);
    const float4 xB0 = *reinterpret_cast<const float4*>(x  + baseB);
    const float4 aB0 = *reinterpret_cast<const float4*>(ae + baseB);
    const float4 xB1 = *reinterpret_cast<const float4*>(x  + baseB + HW_);
    const float4 aB1 = *reinterpret_cast<const float4*>(ae + baseB + HW_);
    const float4 xB2 = *reinterpret_cast<const float4*>(x  + baseB + 2 * HW_);
    const float4 aB2 = *reinterpret_cast<const float4*>(ae + baseB + 2 * HW_);

    wmse_accum(sA, xA0, aA0, xA1, aA1, xA2, aA2, pos_sum, neg_sum, pos_cnt);
    wmse_accum(sB, xB0, aB0, xB1, aB1, xB2, aB2, pos_sum, neg_sum, pos_cnt);
}

__global__ __launch_bounds__(THREADS) void wmse_reduce(
    const float* __restrict__ x,
    const float* __restrict__ ae,
    const float* __restrict__ seg,
    float* __restrict__ ws)   // ws[0..G): pos_sum, [G..2G): neg_sum, [2G..3G): cnt
{
    const int gtid = blockIdx.x * THREADS + threadIdx.x;

    float pos_sum = 0.0f, neg_sum = 0.0f, pos_cnt = 0.0f;

    // Exactly 4 groups/thread: v = gtid + k*STRIDE, k = 0..3, in two 2-group batches.
    wmse_batch2(x, ae, seg, gtid,              gtid +     STRIDE, pos_sum, neg_sum, pos_cnt);
    wmse_batch2(x, ae, seg, gtid + 2 * STRIDE, gtid + 3 * STRIDE, pos_sum, neg_sum, pos_cnt);

    // wave-64 shuffle tree (amortized over 4 groups of work per thread)
#pragma unroll
    for (int off = 32; off >= 1; off >>= 1) {
        pos_sum += __shfl_down(pos_sum, off, 64);
        neg_sum += __shfl_down(neg_sum, off, 64);
        pos_cnt += __shfl_down(pos_cnt, off, 64);
    }

    __shared__ float sp[4], sn[4], sc[4];
    const int wave = threadIdx.x >> 6;
    const int lane = threadIdx.x & 63;
    if (lane == 0) { sp[wave] = pos_sum; sn[wave] = neg_sum; sc[wave] = pos_cnt; }
    __syncthreads();
    if (threadIdx.x == 0) {
        ws[blockIdx.x]             = sp[0] + sp[1] + sp[2] + sp[3];
        ws[GRID1 + blockIdx.x]     = sn[0] + sn[1] + sn[2] + sn[3];
        ws[2 * GRID1 + blockIdx.x] = sc[0] + sc[1] + sc[2] + sc[3];
    }
}

__global__ __launch_bounds__(256) void wmse_stage2(
    const float* __restrict__ ws, float* __restrict__ out)
{
    float pos_sum = 0.0f, neg_sum = 0.0f, pos_cnt = 0.0f;
    for (int i = threadIdx.x; i < GRID1; i += 256) {
        pos_sum += ws[i];
        neg_sum += ws[GRID1 + i];
        pos_cnt += ws[2 * GRID1 + i];
    }

#pragma unroll
    for (int off = 32; off >= 1; off >>= 1) {
        pos_sum += __shfl_down(pos_sum, off, 64);
        neg_sum += __shfl_down(neg_sum, off, 64);
        pos_cnt += __shfl_down(pos_cnt, off, 64);
    }

    __shared__ float sp[4], sn[4], sc[4];
    const int wave = threadIdx.x >> 6;
    const int lane = threadIdx.x & 63;
    if (lane == 0) { sp[wave] = pos_sum; sn[wave] = neg_sum; sc[wave] = pos_cnt; }
    __syncthreads();
    if (threadIdx.x == 0) {
        const float tp = sp[0] + sp[1] + sp[2] + sp[3];
        const float tn = sn[0] + sn[1] + sn[2] + sn[3];
        const float tc = sc[0] + sc[1] + sc[2] + sc[3];

        const float total   = (float)NHW_;
        const float neg_num = total - tc;
        const float pos_ratio = tc / total;
        const float neg_ratio = 1.0f - pos_ratio;
        const float mse_pos = tp / (tc * (float)C_);
        const float mse_neg = tn / (neg_num * (float)C_);
        out[0] = pos_ratio * mse_neg + neg_ratio * mse_pos;
    }
}

extern "C" void kernel_launch(void* const* d_in, const int* in_sizes, int n_in,
                              void* d_out, int out_size, void* d_ws, size_t ws_size,
                              hipStream_t stream) {
    const float* x   = (const float*)d_in[0];
    const float* ae  = (const float*)d_in[1];
    const float* seg = (const float*)d_in[2];
    float* ws  = (float*)d_ws;
    float* out = (float*)d_out;

    wmse_reduce<<<GRID1, THREADS, 0, stream>>>(x, ae, seg, ws);
    wmse_stage2<<<1, 256, 0, stream>>>(ws, out);
}